// Round 1
// baseline (189.069 us; speedup 1.0000x reference)
//
#include <hip/hip_runtime.h>
#include <hip/hip_bf16.h>

#define G      4000
#define BQ     8
#define DEG    32
#define BATCH  128
#define D      32000          // G*BQ
#define NBLK   132000         // G*DEG + G
#define CAP    128            // per-dest bucket capacity (max degree ~60 for seed 0)

// ---------------- CSR build ----------------
__global__ void zero_cnt_kernel(int* cnt) {
    int i = blockIdx.x * 256 + threadIdx.x;
    if (i < G) cnt[i] = 0;
}

__global__ void build_lists_kernel(const int* __restrict__ block_out,
                                   int* __restrict__ cnt,
                                   int* __restrict__ lists) {
    int n = blockIdx.x * 256 + threadIdx.x;
    if (n < NBLK) {
        int dst = block_out[n];
        int pos = atomicAdd(&cnt[dst], 1);
        if (pos < CAP) lists[dst * CAP + pos] = n;
    }
}

// ---------------- transpose x (BATCH, D) -> xg (G, BATCH, 8) ----------------
// Tile: 64 batches x 128 cols (=16 groups). LDS-staged so both sides coalesce.
__global__ __launch_bounds__(256) void transpose_x_kernel(const float* __restrict__ x,
                                                          float* __restrict__ xg) {
    __shared__ float tile[64][132];   // pad 128->132 to spread banks
    int ct = blockIdx.x;              // 0..249 col tile
    int rt = blockIdx.y;              // 0..1   row tile
    int c0 = ct * 128;
    int b0 = rt * 64;
    int t  = threadIdx.x;

#pragma unroll
    for (int it = 0; it < 8; ++it) {
        int l  = it * 1024 + t * 4;
        int br = l >> 7;              // /128
        int c  = l & 127;
        float4 v = *(const float4*)(x + (size_t)(b0 + br) * D + c0 + c);
        *(float4*)&tile[br][c] = v;
    }
    __syncthreads();
#pragma unroll
    for (int it = 0; it < 8; ++it) {
        int l   = it * 1024 + t * 4;
        int gl  = l >> 9;             // /512 -> local group 0..15 over iters
        int rem = l & 511;
        int bl  = rem >> 3;
        int i   = rem & 7;            // 0 or 4
        float4 v = *(const float4*)&tile[bl][gl * 8 + i];
        int gidx = (c0 >> 3) + gl;
        *(float4*)(xg + ((size_t)gidx * BATCH + b0 + bl) * 8 + i) = v;
    }
}

// ---------------- main compute ----------------
// One 128-thread block per destination group; lane = batch index.
// acc[8] in VGPRs, w[n] via scalar loads (uniform n), gather from xg (contiguous 4KB/block).
__global__ __launch_bounds__(128) void compute_kernel(const float* __restrict__ xg,
                                                      const float* __restrict__ w,
                                                      const int* __restrict__ block_in,
                                                      const int* __restrict__ cnt,
                                                      const int* __restrict__ lists,
                                                      float* __restrict__ out) {
    int g = blockIdx.x;               // 0..3999
    int b = threadIdx.x;              // 0..127 (batch)

    // residual init: acc = x[b, g*8 + o]  (coalesced from xg)
    const float4* xr = (const float4*)(xg + ((size_t)g * BATCH + b) * 8);
    float4 r0 = xr[0], r1 = xr[1];
    float acc[8] = { r0.x, r0.y, r0.z, r0.w, r1.x, r1.y, r1.z, r1.w };

    int m = cnt[g];
    if (m > CAP) m = CAP;
    const int* lst = lists + (size_t)g * CAP;

    for (int k = 0; k < m; ++k) {
        int n   = __builtin_amdgcn_readfirstlane(lst[k]);
        int src = __builtin_amdgcn_readfirstlane(block_in[n]);

        const float4* xs = (const float4*)(xg + ((size_t)src * BATCH + b) * 8);
        float4 v0 = xs[0], v1 = xs[1];
        float xi[8] = { v0.x, v0.y, v0.z, v0.w, v1.x, v1.y, v1.z, v1.w };

        const float* wn = w + (size_t)n * 64;   // w[n][i][o], uniform -> s_loads
#pragma unroll
        for (int i = 0; i < 8; ++i) {
#pragma unroll
            for (int o = 0; o < 8; ++o) {
                acc[o] = fmaf(xi[i], wn[i * 8 + o], acc[o]);
            }
        }
    }

    float4 w0 = { acc[0], acc[1], acc[2], acc[3] };
    float4 w1 = { acc[4], acc[5], acc[6], acc[7] };
    float4* op = (float4*)(out + (size_t)b * D + (size_t)g * 8);
    op[0] = w0;
    op[1] = w1;
}

extern "C" void kernel_launch(void* const* d_in, const int* in_sizes, int n_in,
                              void* d_out, int out_size, void* d_ws, size_t ws_size,
                              hipStream_t stream) {
    const float* x         = (const float*)d_in[0];
    const float* w         = (const float*)d_in[1];
    const int*   block_in  = (const int*)d_in[2];
    const int*   block_out = (const int*)d_in[3];
    float*       out       = (float*)d_out;

    // workspace layout
    char* ws = (char*)d_ws;
    int*   cnt   = (int*)ws;                              // 4000 ints (16000 B)
    int*   lists = (int*)(ws + 16384);                    // 512000 ints (2,048,000 B)
    float* xg    = (float*)(ws + 16384 + 2048000);        // 4,096,000 floats (16,384,000 B)

    zero_cnt_kernel<<<(G + 255) / 256, 256, 0, stream>>>(cnt);
    build_lists_kernel<<<(NBLK + 255) / 256, 256, 0, stream>>>(block_out, cnt, lists);
    transpose_x_kernel<<<dim3(D / 128, BATCH / 64), 256, 0, stream>>>(x, xg);
    compute_kernel<<<G, 128, 0, stream>>>(xg, w, block_in, cnt, lists, out);
}